// Round 2
// 189.025 us; speedup vs baseline: 1.0004x; 1.0004x over previous
//
#include <hip/hip_runtime.h>

// HistLoss: per-channel histogram matching + MSE loss.
// C=64, H=W=512, HW=262144, NBINS=256, STRENGTH=100.
//
// R11: identical to R10 (bench infra failed twice; no kernel signal).
// R10: mask bit-compression. Evidence: pass1 requested traffic was
// I(64)+J(64)+mI(64x1MB rereads)+mJ(64x1MB)+pc(32) = 288MB in 57us
// = ~8.2 B/cy/CU, at the VMEM request ceiling (~10), while HBM=21% and
// VALU=18% -- request-bound, half of it mask re-reads served by L2/L3
// but still paying VMEM issue+latency. R9's register dbuf was elided
// (VGPR=56) and couldn't matter under request-boundness.
// Now: k_bits packs mI/mJ into 1 bit/pixel (32KB each) once; pass1
// stages 2KB of bits/slice into LDS (one coalesced load), histJ 512B.
// Mask VMEM requests: 128MB -> ~64KB. Predicates identical (mask in
// {0,1}: >0 <=> bit set); all math/rounding bit-identical to R9:
//   pass1: I-bucket LDS stats, packed u32 (count low12 | 2^28-fx sum
//          high20), per-block partials + qtot quarter totals; J minmax;
//          nI/nJ; Q_c.
//   histJ: per-channel 256-bin masked hist of J -> per-block partials.
//   closs: 4 blocks/channel: hisPart reduce + serial f32 cumsum (ref
//          rounding), analytic arithmetic-series remap, f64 atomic,
//          done-counter writes out.
// Bucket-mean pairing stands in for exact within-bucket ranks (absmax
// 0.0 in R3-R9; threshold 2.9e-6).

#define CN    64
#define HWN   262144
#define NB    256
#define NBUK  8192
#define NBLK  16
#define BPIX  (HWN/NBLK)          // 16384 pixels per pass1 block
#define PT    512                 // pass1 threads
#define XB    64                  // histJ blocks per channel
#define QBUK  (NBUK/4)            // 2048 buckets per closs block
#define FXS2  268435456.0f        // 2^28 fixed-point scale for sum(v-center)
#define FXSI2 (1.0/268435456.0)

// Pack int32 {0,1} masks to 1 bit/pixel. 32768 threads x 8 px each.
__global__ __launch_bounds__(256) void k_bits(
    const int* __restrict__ mI, const int* __restrict__ mJ,
    unsigned char* __restrict__ bI, unsigned char* __restrict__ bJ)
{
  const int t = blockIdx.x*256 + threadIdx.x;
  const int4* a = (const int4*)mI + 2*t;
  int4 x0 = a[0], x1 = a[1];
  unsigned b = (unsigned)((x0.x>0) | ((x0.y>0)<<1) | ((x0.z>0)<<2) | ((x0.w>0)<<3)
             | ((x1.x>0)<<4) | ((x1.y>0)<<5) | ((x1.z>0)<<6) | ((x1.w>0)<<7));
  const int4* c = (const int4*)mJ + 2*t;
  int4 y0 = c[0], y1 = c[1];
  unsigned d = (unsigned)((y0.x>0) | ((y0.y>0)<<1) | ((y0.z>0)<<2) | ((y0.w>0)<<3)
             | ((y1.x>0)<<4) | ((y1.y>0)<<5) | ((y1.z>0)<<6) | ((y1.w>0)<<7));
  bI[t] = (unsigned char)b;
  bJ[t] = (unsigned char)d;
}

__global__ __launch_bounds__(PT, 4) void k_pass1(
    const float* __restrict__ I, const float* __restrict__ J,
    const unsigned* __restrict__ bI, const unsigned* __restrict__ bJ,
    unsigned* __restrict__ pc, unsigned* __restrict__ qtot,
    unsigned* __restrict__ mnp, unsigned* __restrict__ mxp,
    unsigned* __restrict__ cp, double* __restrict__ qp)
{
  const int c = blockIdx.y, q = blockIdx.x, tid = threadIdx.x;
  const int bid = c*NBLK + q;
  const int wid = tid >> 6, lane = tid & 63;
  __shared__ unsigned buk[NBUK];                    // packed (fx<<12)+count
  __shared__ unsigned smbI[BPIX/32], smbJ[BPIX/32]; // 512 words each: slice bits
  __shared__ unsigned sred[PT];
  __shared__ double   dred[PT/64];
  __shared__ unsigned umn[PT/64], umx[PT/64], uci[PT/64], ucj[PT/64];
  for(int i = tid; i < NBUK; i += PT) buk[i] = 0u;
  smbI[tid] = bI[q*(BPIX/32) + tid];                // PT == BPIX/32 == 512
  smbJ[tid] = bJ[q*(BPIX/32) + tid];
  __syncthreads();

  const float4* Ic = (const float4*)(I + (size_t)c*HWN + (size_t)q*BPIX);
  const float4* Jc = (const float4*)(J + (size_t)c*HWN + (size_t)q*BPIX);

  float qacc = 0.0f;
  unsigned ci = 0, cj = 0;
  unsigned mn = 0x7F800000u, mx = 0u;
  const int nsh = (tid & 7) * 4;                    // nibble shift, const/thread

  // 8 float4 groups/thread (group g at idx g*PT+tid), 2-deep reg pipeline.
  // Mask bits for group g: word g*64+(tid>>3), nibble (tid&7)*4 -- LDS
  // broadcast read (8 lanes/word, conflict-free).
  float4 pi[2], pj[2];
  pi[0] = Ic[tid]; pj[0] = Jc[tid];
  #pragma unroll
  for(int g = 0; g < 8; g++){
    const int cur = g & 1, nxt = cur ^ 1;
    if(g < 7){ pi[nxt] = Ic[(g+1)*PT + tid]; pj[nxt] = Jc[(g+1)*PT + tid]; }
    const unsigned bitsI = (smbI[g*64 + (tid>>3)] >> nsh) & 0xFu;
    const unsigned bitsJ = (smbJ[g*64 + (tid>>3)] >> nsh) & 0xFu;
    float4 vi4 = pi[cur], vj4 = pj[cur];
    float vv[4] = {vi4.x, vi4.y, vi4.z, vi4.w};
    #pragma unroll
    for(int e = 0; e < 4; e++){
      if(bitsI & (1u << e)){
        float v = vv[e];
        int k = (int)(v * (float)NBUK);            // pow2 scale: exact, monotone
        if(k > NBUK-1) k = NBUK-1;
        float dv = v - ((float)k + 0.5f) * (1.0f/(float)NBUK);
        int fx = (int)rintf(dv * FXS2);            // |fx| <= 16384
        atomicAdd(&buk[k], ((unsigned)fx << 12) + 1u);
        qacc += dv*dv;
        ci++;
      }
    }
    if(bitsJ & 1u){unsigned u=__float_as_uint(vj4.x); mn=min(mn,u); mx=max(mx,u); cj++;}
    if(bitsJ & 2u){unsigned u=__float_as_uint(vj4.y); mn=min(mn,u); mx=max(mx,u); cj++;}
    if(bitsJ & 4u){unsigned u=__float_as_uint(vj4.z); mn=min(mn,u); mx=max(mx,u); cj++;}
    if(bitsJ & 8u){unsigned u=__float_as_uint(vj4.w); mn=min(mn,u); mx=max(mx,u); cj++;}
  }
  __syncthreads();                                   // LDS atomics complete
  { unsigned* pcb = pc + (size_t)bid * NBUK;
    for(int i = tid; i < NBUK; i += PT) pcb[i] = buk[i]; }

  // per-quarter count totals: thread t sums buk[t*16..t*16+15] (one quarter),
  // 128 threads per quarter, segmented reduce
  { unsigned csum = 0;
    #pragma unroll
    for(int j = 0; j < 16; j++) csum += buk[tid*16 + j] & 0xFFFu;
    sred[tid] = csum; __syncthreads();
    for(int s = 64; s > 0; s >>= 1){
      if((tid & 127) < s) sred[tid] += sred[tid + s];
      __syncthreads();
    }
    if((tid & 127) == 0) qtot[bid*4 + (tid >> 7)] = sred[tid];
  }

  double qd = (double)qacc;
  for(int o = 32; o > 0; o >>= 1){
    qd += __shfl_down(qd, o, 64);
    mn  = min(mn, (unsigned)__shfl_down(mn, o, 64));
    mx  = max(mx, (unsigned)__shfl_down(mx, o, 64));
    ci += __shfl_down(ci, o, 64);
    cj += __shfl_down(cj, o, 64);
  }
  if(lane == 0){ dred[wid]=qd; umn[wid]=mn; umx[wid]=mx; uci[wid]=ci; ucj[wid]=cj; }
  __syncthreads();
  if(tid == 0){
    double t = 0.0; unsigned amn=0x7F800000u, amx=0u, aci=0, acj=0;
    for(int w = 0; w < PT/64; w++){
      t += dred[w];
      amn = min(amn, umn[w]); amx = max(amx, umx[w]);
      aci += uci[w]; acj += ucj[w];
    }
    qp[bid] = t;
    mnp[bid] = amn; mxp[bid] = amx;
    if(c == 0){ cp[2*q] = aci; cp[2*q+1] = acj; }
  }
}

__global__ __launch_bounds__(256) void k_histJ(
    const float* __restrict__ J, const unsigned* __restrict__ bJ,
    const unsigned* __restrict__ mnp, const unsigned* __restrict__ mxp,
    unsigned* __restrict__ hisPart, double* __restrict__ lossacc,
    unsigned* __restrict__ donecnt)
{
  const int c = blockIdx.y, xb = blockIdx.x, tid = threadIdx.x;
  if(c == 0 && xb == 0 && tid == 0){ *lossacc = 0.0; *donecnt = 0u; } // for k_closs
  unsigned mnu = 0x7F800000u, mxu = 0u;
  #pragma unroll
  for(int qi = 0; qi < NBLK; qi++){
    mnu = min(mnu, mnp[c*NBLK + qi]);
    mxu = max(mxu, mxp[c*NBLK + qi]);
  }
  float mnv = __uint_as_float(mnu);
  float den = fmaxf((__uint_as_float(mxu) - mnv) / (float)NB, 1e-12f);
  const int SLICE = HWN/XB;                          // 4096 pixels per block
  __shared__ unsigned h[NB];
  __shared__ unsigned smb[SLICE/32];                 // 128 words: slice bits
  h[tid] = 0u;
  if(tid < SLICE/32) smb[tid] = bJ[xb*(SLICE/32) + tid];
  __syncthreads();
  const float4* Jc = (const float4*)(J + (size_t)c*HWN + (size_t)xb*SLICE);
  const int nsh = (tid & 7) * 4;
  #pragma unroll
  for(int it = 0; it < SLICE/1024; ++it){            // 4 iters
    int idx = it*256 + tid;
    float4 v4 = Jc[idx];
    const unsigned bits = (smb[it*32 + (tid>>3)] >> nsh) & 0xFu;
    float vv[4] = {v4.x,v4.y,v4.z,v4.w};
    #pragma unroll
    for(int e = 0; e < 4; e++){
      if(bits & (1u << e)){
        float bf = floorf((vv[e] - mnv) / den);      // replicate ref: divide, floor, clip
        bf = fminf(fmaxf(bf, 0.0f), 255.0f);
        atomicAdd(&h[(int)bf], 1u);
      }
    }
  }
  __syncthreads();
  hisPart[((size_t)c*XB + xb)*NB + tid] = h[tid];
}

__global__ __launch_bounds__(1024) void k_closs(
    const unsigned* __restrict__ pc, const unsigned* __restrict__ qtot,
    const unsigned* __restrict__ hisPart,
    const unsigned* __restrict__ mnp, const unsigned* __restrict__ mxp,
    const unsigned* __restrict__ cp, const double* __restrict__ qp,
    double* __restrict__ lossacc, unsigned* __restrict__ donecnt,
    float* __restrict__ out)
{
  const int c = blockIdx.x >> 2, qt = blockIdx.x & 3, tid = threadIdx.x;
  const int wid = tid >> 6, lane = tid & 63;
  __shared__ float cs[NB], hs[NB];
  __shared__ unsigned hsum[NB];
  __shared__ unsigned qsh[NBLK*4];
  __shared__ unsigned wsum[16];
  __shared__ double red[16];
  __shared__ float sh_mn, sh_st;
  __shared__ unsigned sh_base;

  if(tid < NB){
    unsigned hr = 0u;
    for(int xb = 0; xb < XB; xb++) hr += hisPart[((size_t)c*XB + xb)*NB + tid];
    hsum[tid] = hr;
  } else if(tid < NB + NBLK*4){
    int k = tid - NB;                                // 16 slices x 4 quarters
    qsh[k] = qtot[(c*NBLK + (k >> 2))*4 + (k & 3)];
  }
  __syncthreads();
  if(tid == 0){
    unsigned ciw = 0, cjw = 0;
    for(int qi = 0; qi < NBLK; qi++){ ciw += cp[2*qi]; cjw += cp[2*qi+1]; }
    float ratio = (float)ciw / (float)cjw;           // nI/nJ in f32, as in ref
    float cum = 0.0f;
    for(int b = 0; b < NB; b++){
      float hh = (float)hsum[b] * ratio;
      hs[b] = hh;
      cum += hh;                                     // sequential f32 == ref rounding
      cs[b] = cum;
    }
    unsigned mnu = 0x7F800000u, mxu = 0u;
    for(int qi = 0; qi < NBLK; qi++){ mnu = min(mnu, mnp[c*NBLK+qi]); mxu = max(mxu, mxp[c*NBLK+qi]); }
    sh_mn = __uint_as_float(mnu);
    sh_st = (__uint_as_float(mxu) - sh_mn) / (float)NB;
    unsigned base = 0;
    for(int s = 0; s < NBLK; s++)
      for(int q2 = 0; q2 < qt; q2++) base += qsh[s*4 + q2];
    sh_base = base;
  }
  __syncthreads();

  // own 2 buckets: b0 = qt*QBUK + tid*2 (+0,+1)
  unsigned  kk[2] = {0,0};
  long long ss[2] = {0,0};
  for(int sl = 0; sl < NBLK; sl++){
    const uint2* pcb = (const uint2*)(pc + (size_t)(c*NBLK + sl)*NBUK + qt*QBUK) + tid;
    uint2 w = *pcb;
    kk[0] += w.x & 0xFFFu;  ss[0] += (int)w.x >> 12; // arithmetic shift: sign-extend sum
    kk[1] += w.y & 0xFFFu;  ss[1] += (int)w.y >> 12;
  }
  unsigned run = kk[0] + kk[1];
  unsigned v = run;                                  // wave inclusive scan
  for(int o = 1; o < 64; o <<= 1){
    unsigned t = __shfl_up(v, o, 64);
    if(lane >= o) v += t;
  }
  if(lane == 63) wsum[wid] = v;
  __syncthreads();
  unsigned wbase = 0;
  for(int w = 0; w < wid; w++) wbase += wsum[w];
  unsigned texcl = sh_base + wbase + (v - run);

  float  mnvf = sh_mn, stepf = sh_st;
  double mnvd = (double)mnvf, stepd = (double)stepf;

  float rf0 = (float)(texcl + 1u);                   // left-search start bin
  int lo = 0, hi = NB;
  while(lo < hi){ int mid = (lo + hi) >> 1; if(cs[mid] < rf0) lo = mid + 1; else hi = mid; }
  int bin = (lo > NB-1) ? NB-1 : lo;

  double acc = 0.0;
  unsigned r = texcl;
  #pragma unroll
  for(int j = 0; j < 2; j++){
    unsigned k = kk[j];
    if(k == 0) continue;
    unsigned ra = r + 1u, rb = r + k; r = rb;
    double sval = 0.0;
    while(ra <= rb){
      while(bin < NB-1 && cs[bin] < (float)ra) bin++;
      float csb = cs[bin], hsb = hs[bin];
      unsigned re = (bin == NB-1) ? rb : min(rb, (unsigned)floorf(csb));
      double lovd = (double)csb - (double)hsb;
      double den2 = fmax((double)hsb, 1e-12);
      double ra_d = (double)ra, re_d = (double)re, nn = (double)(re - ra + 1u);
      double rta = (ra_d - lovd)/den2, rtb = (re_d - lovd)/den2;
      if(hsb > 0.0f && rta >= 0.0 && rtb <= 1.0){
        double sumr = 0.5*(ra_d + re_d)*nn;          // arithmetic series of ranks
        sval += nn*(mnvd + (double)bin*stepd) + stepd*(sumr - nn*lovd)/den2;
      } else {                                       // exact per-rank f32 fallback
        for(unsigned rr = ra; rr <= re; rr++){
          float rf = (float)rr;
          float lov = csb - hsb;
          float rt = (rf - lov) / fmaxf(hsb, 1e-12f);
          rt = fminf(fmaxf(rt, 0.0f), 1.0f);
          sval += (double)(mnvf + ((float)bin + rt)*stepf);
        }
      }
      ra = re + 1u;
    }
    double kb   = (double)k;
    double cb   = ((double)(qt*QBUK + tid*2 + j) + 0.5) * (1.0/(double)NBUK);
    double vbar = sval/kb - cb;                      // mean(val) - bucket center
    double S    = (double)ss[j] * FXSI2;             // sum(v - center)
    acc += kb*vbar*vbar - 2.0*vbar*S;
  }
  if(qt == 0 && tid == 0){                           // Q_c = sum(v-center)^2, once/channel
    double qsum = 0.0;
    for(int qi = 0; qi < NBLK; qi++) qsum += qp[c*NBLK + qi];
    acc += qsum;
  }
  for(int o = 32; o > 0; o >>= 1) acc += __shfl_down(acc, o, 64);
  if(lane == 0) red[wid] = acc;
  __syncthreads();
  if(tid == 0){
    double t = 0.0;
    for(int w = 0; w < 16; w++) t += red[w];
    atomicAdd(lossacc, t);
    __threadfence();
    unsigned old = atomicAdd(donecnt, 1u);
    if(old == (unsigned)(CN*4 - 1)){                 // last block finalizes
      double tot = atomicAdd(lossacc, 0.0);          // coherent read
      out[0] = (float)(tot * (100.0 / (double)((size_t)CN * HWN)));
    }
  }
}

extern "C" void kernel_launch(void* const* d_in, const int* in_sizes, int n_in,
                              void* d_out, int out_size, void* d_ws, size_t ws_size,
                              hipStream_t stream){
  const float* I  = (const float*)d_in[0];
  const float* J  = (const float*)d_in[1];
  const int*   mI = (const int*)d_in[2];
  const int*   mJ = (const int*)d_in[3];
  float* out = (float*)d_out;

  char* base = (char*)d_ws;
  size_t pcB = (size_t)CN * NBLK * NBUK * sizeof(unsigned);      // 32 MB
  size_t hpB = (size_t)CN * XB * NB * sizeof(unsigned);          // 4 MB
  size_t qtB = (size_t)CN * NBLK * 4 * sizeof(unsigned);         // 16 KB
  unsigned* pc      = (unsigned*)base;
  unsigned* hisPart = (unsigned*)(base + pcB);
  unsigned* qtot    = (unsigned*)(base + pcB + hpB);
  char* p = base + pcB + hpB + qtB;
  double*   qp      = (double*)p;   p += (size_t)CN*NBLK*sizeof(double);
  double*   lossacc = (double*)p;   p += sizeof(double);
  unsigned* mnp     = (unsigned*)p; p += (size_t)CN*NBLK*sizeof(unsigned);
  unsigned* mxp     = (unsigned*)p; p += (size_t)CN*NBLK*sizeof(unsigned);
  unsigned* cp      = (unsigned*)p; p += 2*NBLK*sizeof(unsigned);
  unsigned* donecnt = (unsigned*)p; p += sizeof(unsigned);
  size_t off = (size_t)(p - base); off = (off + 15) & ~(size_t)15;
  unsigned char* bIb = (unsigned char*)(base + off);             // 32 KB bitmask
  unsigned char* bJb = bIb + HWN/8;                              // 32 KB bitmask

  k_bits<<<HWN/(8*256), 256, 0, stream>>>(mI, mJ, bIb, bJb);
  k_pass1<<<dim3(NBLK, CN), PT, 0, stream>>>(I, J, (const unsigned*)bIb,
                                             (const unsigned*)bJb, pc, qtot,
                                             mnp, mxp, cp, qp);
  k_histJ<<<dim3(XB, CN), 256, 0, stream>>>(J, (const unsigned*)bJb, mnp, mxp,
                                            hisPart, lossacc, donecnt);
  k_closs<<<CN*4, 1024, 0, stream>>>(pc, qtot, hisPart, mnp, mxp, cp, qp,
                                     lossacc, donecnt, out);
}

// Round 3
// 188.108 us; speedup vs baseline: 1.0053x; 1.0049x over previous
//
#include <hip/hip_runtime.h>

// HistLoss: per-channel histogram matching + MSE loss.
// C=64, H=W=512, HW=262144, NBINS=256, STRENGTH=100.
//
// R12: MLP (memory-level-parallelism) push. Evidence from R10 run:
// pass1 at 160MB/52us = 4.4 B/cy/CU << ~10 request ceiling, VALU 21%,
// HBM 25%, bank-conflicts 3% -- latency-bound. VGPR_Count=40 shows the
// compiler collapsed the 2-deep software pipeline (~2 loads in
// flight/thread). Total pinned at 189 while pass1 dropped 5us => ~135us
// in histJ/closs/bubbles; histJ (256-thr blocks, 4 loads/thread) has
// the same MLP starvation.
// Now: (a) pass1 issues ALL 16 float4 loads (8 I + 8 J) into named
// registers up front, __launch_bounds__(512,2) to permit ~100+ VGPR;
// (b) histJ restructured to 512-thr/16384-px blocks (XB=16) with all 8
// J-loads up front, same bit-mask LDS staging; (c) closs hisPart reduce
// uses all 1024 threads (4 partials x 16->4 xb each).
// All math/rounding/atomic semantics bit-identical to R10 (absmax 0.0):
//   pass1: I-bucket LDS stats, packed u32 (count low12 | 2^28-fx sum
//          high20), per-block partials + qtot quarter totals; J minmax;
//          nI/nJ; Q_c.
//   histJ: per-channel 256-bin masked hist of J -> per-block partials.
//   closs: 4 blocks/channel: hisPart reduce + serial f32 cumsum (ref
//          rounding), analytic arithmetic-series remap, f64 atomic,
//          done-counter writes out.
// Bucket-mean pairing stands in for exact within-bucket ranks (absmax
// 0.0 in R3-R11; threshold 2.9e-6).

#define CN    64
#define HWN   262144
#define NB    256
#define NBUK  8192
#define NBLK  16
#define BPIX  (HWN/NBLK)          // 16384 pixels per pass1 block
#define PT    512                 // pass1 threads
#define XB    16                  // histJ blocks per channel (R12: was 64)
#define JSL   (HWN/XB)            // 16384 pixels per histJ block
#define QBUK  (NBUK/4)            // 2048 buckets per closs block
#define FXS2  268435456.0f        // 2^28 fixed-point scale for sum(v-center)
#define FXSI2 (1.0/268435456.0)

// Pack int32 {0,1} masks to 1 bit/pixel. 32768 threads x 8 px each.
__global__ __launch_bounds__(256) void k_bits(
    const int* __restrict__ mI, const int* __restrict__ mJ,
    unsigned char* __restrict__ bI, unsigned char* __restrict__ bJ)
{
  const int t = blockIdx.x*256 + threadIdx.x;
  const int4* a = (const int4*)mI + 2*t;
  int4 x0 = a[0], x1 = a[1];
  unsigned b = (unsigned)((x0.x>0) | ((x0.y>0)<<1) | ((x0.z>0)<<2) | ((x0.w>0)<<3)
             | ((x1.x>0)<<4) | ((x1.y>0)<<5) | ((x1.z>0)<<6) | ((x1.w>0)<<7));
  const int4* c = (const int4*)mJ + 2*t;
  int4 y0 = c[0], y1 = c[1];
  unsigned d = (unsigned)((y0.x>0) | ((y0.y>0)<<1) | ((y0.z>0)<<2) | ((y0.w>0)<<3)
             | ((y1.x>0)<<4) | ((y1.y>0)<<5) | ((y1.z>0)<<6) | ((y1.w>0)<<7));
  bI[t] = (unsigned char)b;
  bJ[t] = (unsigned char)d;
}

__device__ __forceinline__ void px_i(float v, float& qacc, unsigned& ci,
                                     unsigned* buk){
  int k = (int)(v * (float)NBUK);                    // pow2 scale: exact, monotone
  if(k > NBUK-1) k = NBUK-1;
  float dv = v - ((float)k + 0.5f) * (1.0f/(float)NBUK);
  int fx = (int)rintf(dv * FXS2);                    // |fx| <= 16384
  atomicAdd(&buk[k], ((unsigned)fx << 12) + 1u);
  qacc += dv*dv;
  ci++;
}

__device__ __forceinline__ void grp_p1(float4 vi4, float4 vj4,
    unsigned bitsI, unsigned bitsJ, float& qacc, unsigned& ci, unsigned& cj,
    unsigned& mn, unsigned& mx, unsigned* buk){
  if(bitsI & 1u) px_i(vi4.x, qacc, ci, buk);
  if(bitsI & 2u) px_i(vi4.y, qacc, ci, buk);
  if(bitsI & 4u) px_i(vi4.z, qacc, ci, buk);
  if(bitsI & 8u) px_i(vi4.w, qacc, ci, buk);
  if(bitsJ & 1u){unsigned u=__float_as_uint(vj4.x); mn=min(mn,u); mx=max(mx,u); cj++;}
  if(bitsJ & 2u){unsigned u=__float_as_uint(vj4.y); mn=min(mn,u); mx=max(mx,u); cj++;}
  if(bitsJ & 4u){unsigned u=__float_as_uint(vj4.z); mn=min(mn,u); mx=max(mx,u); cj++;}
  if(bitsJ & 8u){unsigned u=__float_as_uint(vj4.w); mn=min(mn,u); mx=max(mx,u); cj++;}
}

__global__ __launch_bounds__(PT, 2) void k_pass1(
    const float* __restrict__ I, const float* __restrict__ J,
    const unsigned* __restrict__ bI, const unsigned* __restrict__ bJ,
    unsigned* __restrict__ pc, unsigned* __restrict__ qtot,
    unsigned* __restrict__ mnp, unsigned* __restrict__ mxp,
    unsigned* __restrict__ cp, double* __restrict__ qp)
{
  const int c = blockIdx.y, q = blockIdx.x, tid = threadIdx.x;
  const int bid = c*NBLK + q;
  const int wid = tid >> 6, lane = tid & 63;
  __shared__ unsigned buk[NBUK];                    // packed (fx<<12)+count
  __shared__ unsigned smbI[BPIX/32], smbJ[BPIX/32]; // 512 words each: slice bits
  __shared__ unsigned sred[PT];
  __shared__ double   dred[PT/64];
  __shared__ unsigned umn[PT/64], umx[PT/64], uci[PT/64], ucj[PT/64];
  for(int i = tid; i < NBUK; i += PT) buk[i] = 0u;
  smbI[tid] = bI[q*(BPIX/32) + tid];                // PT == BPIX/32 == 512
  smbJ[tid] = bJ[q*(BPIX/32) + tid];
  __syncthreads();

  const float4* Ic = (const float4*)(I + (size_t)c*HWN + (size_t)q*BPIX);
  const float4* Jc = (const float4*)(J + (size_t)c*HWN + (size_t)q*BPIX);

  float qacc = 0.0f;
  unsigned ci = 0, cj = 0;
  unsigned mn = 0x7F800000u, mx = 0u;
  const int nsh = (tid & 7) * 4;                    // nibble shift, const/thread
  const int bw  = tid >> 3;                         // bit-word sub-index

  // Issue ALL 16 global loads up front (named regs, static idx only) --
  // max MLP: ~16 loads in flight/thread while group 0 processes.
  float4 i0 = Ic[0*PT+tid], i1 = Ic[1*PT+tid], i2 = Ic[2*PT+tid], i3 = Ic[3*PT+tid];
  float4 i4 = Ic[4*PT+tid], i5 = Ic[5*PT+tid], i6 = Ic[6*PT+tid], i7 = Ic[7*PT+tid];
  float4 j0 = Jc[0*PT+tid], j1 = Jc[1*PT+tid], j2 = Jc[2*PT+tid], j3 = Jc[3*PT+tid];
  float4 j4 = Jc[4*PT+tid], j5 = Jc[5*PT+tid], j6 = Jc[6*PT+tid], j7 = Jc[7*PT+tid];
  unsigned wi0=smbI[0*64+bw], wi1=smbI[1*64+bw], wi2=smbI[2*64+bw], wi3=smbI[3*64+bw];
  unsigned wi4=smbI[4*64+bw], wi5=smbI[5*64+bw], wi6=smbI[6*64+bw], wi7=smbI[7*64+bw];
  unsigned wj0=smbJ[0*64+bw], wj1=smbJ[1*64+bw], wj2=smbJ[2*64+bw], wj3=smbJ[3*64+bw];
  unsigned wj4=smbJ[4*64+bw], wj5=smbJ[5*64+bw], wj6=smbJ[6*64+bw], wj7=smbJ[7*64+bw];

  grp_p1(i0, j0, (wi0>>nsh)&0xFu, (wj0>>nsh)&0xFu, qacc, ci, cj, mn, mx, buk);
  grp_p1(i1, j1, (wi1>>nsh)&0xFu, (wj1>>nsh)&0xFu, qacc, ci, cj, mn, mx, buk);
  grp_p1(i2, j2, (wi2>>nsh)&0xFu, (wj2>>nsh)&0xFu, qacc, ci, cj, mn, mx, buk);
  grp_p1(i3, j3, (wi3>>nsh)&0xFu, (wj3>>nsh)&0xFu, qacc, ci, cj, mn, mx, buk);
  grp_p1(i4, j4, (wi4>>nsh)&0xFu, (wj4>>nsh)&0xFu, qacc, ci, cj, mn, mx, buk);
  grp_p1(i5, j5, (wi5>>nsh)&0xFu, (wj5>>nsh)&0xFu, qacc, ci, cj, mn, mx, buk);
  grp_p1(i6, j6, (wi6>>nsh)&0xFu, (wj6>>nsh)&0xFu, qacc, ci, cj, mn, mx, buk);
  grp_p1(i7, j7, (wi7>>nsh)&0xFu, (wj7>>nsh)&0xFu, qacc, ci, cj, mn, mx, buk);

  __syncthreads();                                   // LDS atomics complete
  { unsigned* pcb = pc + (size_t)bid * NBUK;
    for(int i = tid; i < NBUK; i += PT) pcb[i] = buk[i]; }

  // per-quarter count totals: thread t sums buk[t*16..t*16+15] (one quarter),
  // 128 threads per quarter, segmented reduce
  { unsigned csum = 0;
    #pragma unroll
    for(int j = 0; j < 16; j++) csum += buk[tid*16 + j] & 0xFFFu;
    sred[tid] = csum; __syncthreads();
    for(int s = 64; s > 0; s >>= 1){
      if((tid & 127) < s) sred[tid] += sred[tid + s];
      __syncthreads();
    }
    if((tid & 127) == 0) qtot[bid*4 + (tid >> 7)] = sred[tid];
  }

  double qd = (double)qacc;
  for(int o = 32; o > 0; o >>= 1){
    qd += __shfl_down(qd, o, 64);
    mn  = min(mn, (unsigned)__shfl_down(mn, o, 64));
    mx  = max(mx, (unsigned)__shfl_down(mx, o, 64));
    ci += __shfl_down(ci, o, 64);
    cj += __shfl_down(cj, o, 64);
  }
  if(lane == 0){ dred[wid]=qd; umn[wid]=mn; umx[wid]=mx; uci[wid]=ci; ucj[wid]=cj; }
  __syncthreads();
  if(tid == 0){
    double t = 0.0; unsigned amn=0x7F800000u, amx=0u, aci=0, acj=0;
    for(int w = 0; w < PT/64; w++){
      t += dred[w];
      amn = min(amn, umn[w]); amx = max(amx, umx[w]);
      aci += uci[w]; acj += ucj[w];
    }
    qp[bid] = t;
    mnp[bid] = amn; mxp[bid] = amx;
    if(c == 0){ cp[2*q] = aci; cp[2*q+1] = acj; }
  }
}

__device__ __forceinline__ void grp_hj(float4 v4, unsigned bits,
    float mnv, float den, unsigned* h){
  if(bits & 1u){
    float bf = floorf((v4.x - mnv) / den);
    bf = fminf(fmaxf(bf, 0.0f), 255.0f);
    atomicAdd(&h[(int)bf], 1u);
  }
  if(bits & 2u){
    float bf = floorf((v4.y - mnv) / den);
    bf = fminf(fmaxf(bf, 0.0f), 255.0f);
    atomicAdd(&h[(int)bf], 1u);
  }
  if(bits & 4u){
    float bf = floorf((v4.z - mnv) / den);
    bf = fminf(fmaxf(bf, 0.0f), 255.0f);
    atomicAdd(&h[(int)bf], 1u);
  }
  if(bits & 8u){
    float bf = floorf((v4.w - mnv) / den);
    bf = fminf(fmaxf(bf, 0.0f), 255.0f);
    atomicAdd(&h[(int)bf], 1u);
  }
}

__global__ __launch_bounds__(512, 2) void k_histJ(
    const float* __restrict__ J, const unsigned* __restrict__ bJ,
    const unsigned* __restrict__ mnp, const unsigned* __restrict__ mxp,
    unsigned* __restrict__ hisPart, double* __restrict__ lossacc,
    unsigned* __restrict__ donecnt)
{
  const int c = blockIdx.y, xb = blockIdx.x, tid = threadIdx.x;
  if(c == 0 && xb == 0 && tid == 0){ *lossacc = 0.0; *donecnt = 0u; } // for k_closs
  unsigned mnu = 0x7F800000u, mxu = 0u;
  #pragma unroll
  for(int qi = 0; qi < NBLK; qi++){
    mnu = min(mnu, mnp[c*NBLK + qi]);
    mxu = max(mxu, mxp[c*NBLK + qi]);
  }
  float mnv = __uint_as_float(mnu);
  float den = fmaxf((__uint_as_float(mxu) - mnv) / (float)NB, 1e-12f);
  __shared__ unsigned h[NB];
  __shared__ unsigned smb[JSL/32];                   // 512 words: slice bits
  if(tid < NB) h[tid] = 0u;
  smb[tid] = bJ[xb*(JSL/32) + tid];                  // 512 threads == 512 words
  __syncthreads();
  const float4* Jc = (const float4*)(J + (size_t)c*HWN + (size_t)xb*JSL);
  const int nsh = (tid & 7) * 4;
  const int bw  = tid >> 3;
  // all 8 loads up front (same MLP shape as pass1)
  float4 v0 = Jc[0*512+tid], v1 = Jc[1*512+tid], v2 = Jc[2*512+tid], v3 = Jc[3*512+tid];
  float4 v4 = Jc[4*512+tid], v5 = Jc[5*512+tid], v6 = Jc[6*512+tid], v7 = Jc[7*512+tid];
  unsigned w0=smb[0*64+bw], w1=smb[1*64+bw], w2=smb[2*64+bw], w3=smb[3*64+bw];
  unsigned w4=smb[4*64+bw], w5=smb[5*64+bw], w6=smb[6*64+bw], w7=smb[7*64+bw];
  grp_hj(v0, (w0>>nsh)&0xFu, mnv, den, h);
  grp_hj(v1, (w1>>nsh)&0xFu, mnv, den, h);
  grp_hj(v2, (w2>>nsh)&0xFu, mnv, den, h);
  grp_hj(v3, (w3>>nsh)&0xFu, mnv, den, h);
  grp_hj(v4, (w4>>nsh)&0xFu, mnv, den, h);
  grp_hj(v5, (w5>>nsh)&0xFu, mnv, den, h);
  grp_hj(v6, (w6>>nsh)&0xFu, mnv, den, h);
  grp_hj(v7, (w7>>nsh)&0xFu, mnv, den, h);
  __syncthreads();
  if(tid < NB) hisPart[((size_t)c*XB + xb)*NB + tid] = h[tid];
}

__global__ __launch_bounds__(1024) void k_closs(
    const unsigned* __restrict__ pc, const unsigned* __restrict__ qtot,
    const unsigned* __restrict__ hisPart,
    const unsigned* __restrict__ mnp, const unsigned* __restrict__ mxp,
    const unsigned* __restrict__ cp, const double* __restrict__ qp,
    double* __restrict__ lossacc, unsigned* __restrict__ donecnt,
    float* __restrict__ out)
{
  const int c = blockIdx.x >> 2, qt = blockIdx.x & 3, tid = threadIdx.x;
  const int wid = tid >> 6, lane = tid & 63;
  __shared__ float cs[NB], hs[NB];
  __shared__ unsigned hsum[NB];
  __shared__ unsigned ph[4][NB];
  __shared__ unsigned qsh[NBLK*4];
  __shared__ unsigned wsum[16];
  __shared__ double red[16];
  __shared__ float sh_mn, sh_st;
  __shared__ unsigned sh_base;

  // all 1024 threads reduce hisPart: bin = tid&255, part = tid>>8 (4 xb each)
  { const int part = tid >> 8, bin = tid & 255;
    unsigned hr = 0u;
    #pragma unroll
    for(int x = 0; x < 4; x++)
      hr += hisPart[((size_t)c*XB + (part*4 + x))*NB + bin];
    ph[part][bin] = hr; }
  if(tid < NBLK*4)                                   // 16 slices x 4 quarters
    qsh[tid] = qtot[(c*NBLK + (tid >> 2))*4 + (tid & 3)];
  __syncthreads();
  if(tid < NB) hsum[tid] = ph[0][tid] + ph[1][tid] + ph[2][tid] + ph[3][tid];
  __syncthreads();
  if(tid == 0){
    unsigned ciw = 0, cjw = 0;
    for(int qi = 0; qi < NBLK; qi++){ ciw += cp[2*qi]; cjw += cp[2*qi+1]; }
    float ratio = (float)ciw / (float)cjw;           // nI/nJ in f32, as in ref
    float cum = 0.0f;
    for(int b = 0; b < NB; b++){
      float hh = (float)hsum[b] * ratio;
      hs[b] = hh;
      cum += hh;                                     // sequential f32 == ref rounding
      cs[b] = cum;
    }
    unsigned mnu = 0x7F800000u, mxu = 0u;
    for(int qi = 0; qi < NBLK; qi++){ mnu = min(mnu, mnp[c*NBLK+qi]); mxu = max(mxu, mxp[c*NBLK+qi]); }
    sh_mn = __uint_as_float(mnu);
    sh_st = (__uint_as_float(mxu) - sh_mn) / (float)NB;
    unsigned base = 0;
    for(int s = 0; s < NBLK; s++)
      for(int q2 = 0; q2 < qt; q2++) base += qsh[s*4 + q2];
    sh_base = base;
  }
  __syncthreads();

  // own 2 buckets: b0 = qt*QBUK + tid*2 (+0,+1)
  unsigned  kk[2] = {0,0};
  long long ss[2] = {0,0};
  for(int sl = 0; sl < NBLK; sl++){
    const uint2* pcb = (const uint2*)(pc + (size_t)(c*NBLK + sl)*NBUK + qt*QBUK) + tid;
    uint2 w = *pcb;
    kk[0] += w.x & 0xFFFu;  ss[0] += (int)w.x >> 12; // arithmetic shift: sign-extend sum
    kk[1] += w.y & 0xFFFu;  ss[1] += (int)w.y >> 12;
  }
  unsigned run = kk[0] + kk[1];
  unsigned v = run;                                  // wave inclusive scan
  for(int o = 1; o < 64; o <<= 1){
    unsigned t = __shfl_up(v, o, 64);
    if(lane >= o) v += t;
  }
  if(lane == 63) wsum[wid] = v;
  __syncthreads();
  unsigned wbase = 0;
  for(int w = 0; w < wid; w++) wbase += wsum[w];
  unsigned texcl = sh_base + wbase + (v - run);

  float  mnvf = sh_mn, stepf = sh_st;
  double mnvd = (double)mnvf, stepd = (double)stepf;

  float rf0 = (float)(texcl + 1u);                   // left-search start bin
  int lo = 0, hi = NB;
  while(lo < hi){ int mid = (lo + hi) >> 1; if(cs[mid] < rf0) lo = mid + 1; else hi = mid; }
  int bin = (lo > NB-1) ? NB-1 : lo;

  double acc = 0.0;
  unsigned r = texcl;
  #pragma unroll
  for(int j = 0; j < 2; j++){
    unsigned k = kk[j];
    if(k == 0) continue;
    unsigned ra = r + 1u, rb = r + k; r = rb;
    double sval = 0.0;
    while(ra <= rb){
      while(bin < NB-1 && cs[bin] < (float)ra) bin++;
      float csb = cs[bin], hsb = hs[bin];
      unsigned re = (bin == NB-1) ? rb : min(rb, (unsigned)floorf(csb));
      double lovd = (double)csb - (double)hsb;
      double den2 = fmax((double)hsb, 1e-12);
      double ra_d = (double)ra, re_d = (double)re, nn = (double)(re - ra + 1u);
      double rta = (ra_d - lovd)/den2, rtb = (re_d - lovd)/den2;
      if(hsb > 0.0f && rta >= 0.0 && rtb <= 1.0){
        double sumr = 0.5*(ra_d + re_d)*nn;          // arithmetic series of ranks
        sval += nn*(mnvd + (double)bin*stepd) + stepd*(sumr - nn*lovd)/den2;
      } else {                                       // exact per-rank f32 fallback
        for(unsigned rr = ra; rr <= re; rr++){
          float rf = (float)rr;
          float lov = csb - hsb;
          float rt = (rf - lov) / fmaxf(hsb, 1e-12f);
          rt = fminf(fmaxf(rt, 0.0f), 1.0f);
          sval += (double)(mnvf + ((float)bin + rt)*stepf);
        }
      }
      ra = re + 1u;
    }
    double kb   = (double)k;
    double cb   = ((double)(qt*QBUK + tid*2 + j) + 0.5) * (1.0/(double)NBUK);
    double vbar = sval/kb - cb;                      // mean(val) - bucket center
    double S    = (double)ss[j] * FXSI2;             // sum(v - center)
    acc += kb*vbar*vbar - 2.0*vbar*S;
  }
  if(qt == 0 && tid == 0){                           // Q_c = sum(v-center)^2, once/channel
    double qsum = 0.0;
    for(int qi = 0; qi < NBLK; qi++) qsum += qp[c*NBLK + qi];
    acc += qsum;
  }
  for(int o = 32; o > 0; o >>= 1) acc += __shfl_down(acc, o, 64);
  if(lane == 0) red[wid] = acc;
  __syncthreads();
  if(tid == 0){
    double t = 0.0;
    for(int w = 0; w < 16; w++) t += red[w];
    atomicAdd(lossacc, t);
    __threadfence();
    unsigned old = atomicAdd(donecnt, 1u);
    if(old == (unsigned)(CN*4 - 1)){                 // last block finalizes
      double tot = atomicAdd(lossacc, 0.0);          // coherent read
      out[0] = (float)(tot * (100.0 / (double)((size_t)CN * HWN)));
    }
  }
}

extern "C" void kernel_launch(void* const* d_in, const int* in_sizes, int n_in,
                              void* d_out, int out_size, void* d_ws, size_t ws_size,
                              hipStream_t stream){
  const float* I  = (const float*)d_in[0];
  const float* J  = (const float*)d_in[1];
  const int*   mI = (const int*)d_in[2];
  const int*   mJ = (const int*)d_in[3];
  float* out = (float*)d_out;

  char* base = (char*)d_ws;
  size_t pcB = (size_t)CN * NBLK * NBUK * sizeof(unsigned);      // 32 MB
  size_t hpB = (size_t)CN * XB * NB * sizeof(unsigned);          // 1 MB
  size_t qtB = (size_t)CN * NBLK * 4 * sizeof(unsigned);         // 16 KB
  unsigned* pc      = (unsigned*)base;
  unsigned* hisPart = (unsigned*)(base + pcB);
  unsigned* qtot    = (unsigned*)(base + pcB + hpB);
  char* p = base + pcB + hpB + qtB;
  double*   qp      = (double*)p;   p += (size_t)CN*NBLK*sizeof(double);
  double*   lossacc = (double*)p;   p += sizeof(double);
  unsigned* mnp     = (unsigned*)p; p += (size_t)CN*NBLK*sizeof(unsigned);
  unsigned* mxp     = (unsigned*)p; p += (size_t)CN*NBLK*sizeof(unsigned);
  unsigned* cp      = (unsigned*)p; p += 2*NBLK*sizeof(unsigned);
  unsigned* donecnt = (unsigned*)p; p += sizeof(unsigned);
  size_t off = (size_t)(p - base); off = (off + 15) & ~(size_t)15;
  unsigned char* bIb = (unsigned char*)(base + off);             // 32 KB bitmask
  unsigned char* bJb = bIb + HWN/8;                              // 32 KB bitmask

  k_bits<<<HWN/(8*256), 256, 0, stream>>>(mI, mJ, bIb, bJb);
  k_pass1<<<dim3(NBLK, CN), PT, 0, stream>>>(I, J, (const unsigned*)bIb,
                                             (const unsigned*)bJb, pc, qtot,
                                             mnp, mxp, cp, qp);
  k_histJ<<<dim3(XB, CN), 512, 0, stream>>>(J, (const unsigned*)bJb, mnp, mxp,
                                            hisPart, lossacc, donecnt);
  k_closs<<<CN*4, 1024, 0, stream>>>(pc, qtot, hisPart, mnp, mxp, cp, qp,
                                     lossacc, donecnt, out);
}